// Round 12
// baseline (71.273 us; speedup 1.0000x reference)
//
#include <hip/hip_runtime.h>

#define NB     32
#define NKEYS  2048
#define D      512
#define NSLICE 32                  // v-slices per batch (16 floats each)
#define SLW    (D / NSLICE)        // 16 floats = 4 float4 per slice

__device__ __forceinline__ float wave_sum(float v) {
    #pragma unroll
    for (int o = 32; o > 0; o >>= 1) v += __shfl_xor(v, o);
    return v;
}
__device__ __forceinline__ float dot8(float4 a, float4 b, float4 c, float4 d) {
    return a.x * b.x + a.y * b.y + a.z * b.z + a.w * b.w
         + c.x * d.x + c.y * d.y + c.z * d.z + c.w * d.w;
}

// blocks 0..511: wkh[dk] = Wk[dk,:]·Wh ; wqh[dk] = Wq[dk,:]·Wh
// block 512:     cbias = (bk+bq)·Wh + bh
__global__ __launch_bounds__(256) void prep_kernel(const float* __restrict__ Wk,
        const float* __restrict__ Wq, const float* __restrict__ Wh,
        const float* __restrict__ bk, const float* __restrict__ bq,
        const float* __restrict__ bh,
        float* __restrict__ wkh, float* __restrict__ wqh, float* __restrict__ cbias) {
    int tid = threadIdx.x, lane = tid & 63, wv = tid >> 6;
    __shared__ float sred[8];
    if (blockIdx.x < D) {
        int dk = blockIdx.x;
        float sk = 0.f, sq = 0.f;
        #pragma unroll
        for (int h = tid; h < D; h += 256) {
            float wh = Wh[h];
            sk = fmaf(Wk[dk * D + h], wh, sk);
            sq = fmaf(Wq[dk * D + h], wh, sq);
        }
        sk = wave_sum(sk); sq = wave_sum(sq);
        if (lane == 0) { sred[wv] = sk; sred[wv + 4] = sq; }
        __syncthreads();
        if (tid == 0) wkh[dk] = sred[0] + sred[1] + sred[2] + sred[3];
        if (tid == 1) wqh[dk] = sred[4] + sred[5] + sred[6] + sred[7];
    } else {
        float s = 0.f;
        #pragma unroll
        for (int h = tid; h < D; h += 256) s = fmaf(bk[h] + bq[h], Wh[h], s);
        s = wave_sum(s);
        if (lane == 0) sred[wv] = s;
        __syncthreads();
        if (tid == 0) cbias[0] = sred[0] + sred[1] + sred[2] + sred[3] + bh[0];
    }
}

// p[b,n] = exp(relu(K[b,n,:]·wkh + qd_b)); 8 rows/block, 2 rows/wave with
// both rows' loads in flight before the shuffle chains. Wave 0 computes qd.
// 256 blocks/batch — no straddle. grid: 8192 blocks x 256 threads.
__global__ __launch_bounds__(256) void energy_kernel(const float* __restrict__ K,
        const float* __restrict__ Q, const float* __restrict__ wkh,
        const float* __restrict__ wqh, const float* __restrict__ cbias,
        float* __restrict__ p) {
    int tid  = threadIdx.x;
    int lane = tid & 63, wv = tid >> 6;
    long row0 = (long)blockIdx.x * 8;
    int b = (int)(row0 >> 11);
    long rA = row0 + wv, rB = row0 + 4 + wv;
    __shared__ float qds;

    // issue both rows' K loads + wkh loads up-front
    const float4* krA = (const float4*)(K + rA * D);
    const float4* krB = (const float4*)(K + rB * D);
    const float4* wr  = (const float4*)wkh;
    float4 a0 = krA[lane], a1 = krA[lane + 64];
    float4 b0 = krB[lane], b1 = krB[lane + 64];
    float4 w0 = wr[lane],  w1 = wr[lane + 64];

    if (wv == 0) {                                   // wave 0: qd for batch b
        const float4* q4  = (const float4*)(Q + b * D);
        const float4* wq4 = (const float4*)wqh;
        float qd = dot8(q4[lane], wq4[lane], q4[lane + 64], wq4[lane + 64]);
        qd = wave_sum(qd);
        if (lane == 0) qds = qd + cbias[0];
    }

    float sA = dot8(a0, w0, a1, w1);
    float sB = dot8(b0, w0, b1, w1);
    sA = wave_sum(sA);
    sB = wave_sum(sB);
    __syncthreads();                                 // qds ready
    // relu bounds energies; exp without max-shift is fp32-safe and cancels
    // identically after normalization.
    if (lane == 0) {
        p[rA] = expf(fmaxf(sA + qds, 0.f));
        p[rB] = expf(fmaxf(sB + qds, 0.f));
    }
}

// Block (b, slice): S_b from LDS-cached p (8KB, L2-hot), stream V[b,:,slice]
// (64B-granular float4 reads), write FINAL out slice + wout strip.
// grid: NB*NSLICE = 1024 blocks x 256 threads (4 blocks/CU).
__global__ __launch_bounds__(256) void vfinal_kernel(const float* __restrict__ V,
        const float* __restrict__ p, float* __restrict__ out,
        float* __restrict__ wout) {
    int slice = blockIdx.x & (NSLICE - 1);
    int b     = blockIdx.x >> 5;
    int tid   = threadIdx.x, lane = tid & 63, wv = tid >> 6;

    __shared__ float pl[NKEYS];                      // 8 KB
    __shared__ float sredf[4];
    __shared__ float4 red[256];                      // 4 KB

    // load p[b,:] to LDS + block sum
    const float4* p4 = (const float4*)(p + b * NKEYS);
    float4* pl4 = (float4*)pl;
    float s = 0.f;
    #pragma unroll
    for (int i = 0; i < 2; ++i) {
        float4 v = p4[tid + i * 256];
        pl4[tid + i * 256] = v;
        s += v.x + v.y + v.z + v.w;
    }
    s = wave_sum(s);
    if (lane == 0) sredf[wv] = s;
    __syncthreads();
    float inv = 1.f / (sredf[0] + sredf[1] + sredf[2] + sredf[3]);

    // V stream: thread owns float4 slot v4i of the slice, row-group rg
    int v4i = tid & 3;                               // 0..3
    int rg  = tid >> 2;                              // 0..63
    const float4* vb = (const float4*)(V + (long)b * NKEYS * D);
    int colbase = slice * (SLW / 4);                 // slice*4
    float4 acc = {0.f, 0.f, 0.f, 0.f};
    #pragma unroll 8
    for (int pass = 0; pass < NKEYS / 64; ++pass) {  // 32 passes
        int n = pass * 64 + rg;
        float w = pl[n];
        float4 vv = vb[(long)n * (D / 4) + colbase + v4i];
        acc.x = fmaf(w, vv.x, acc.x);
        acc.y = fmaf(w, vv.y, acc.y);
        acc.z = fmaf(w, vv.z, acc.z);
        acc.w = fmaf(w, vv.w, acc.w);
    }

    // wout strip: 64 weights per block (after the stream — off critical path)
    int n0 = slice * (NKEYS / NSLICE);
    if (tid < NKEYS / NSLICE) wout[b * NKEYS + n0 + tid] = pl[n0 + tid] * inv;

    // tree-combine 64 row-groups per v4 slot
    red[tid] = acc;
    __syncthreads();
    #pragma unroll
    for (int g = 128; g >= 4; g >>= 1) {
        if (tid < g) {
            float4 o = red[tid + g];
            red[tid].x += o.x; red[tid].y += o.y;
            red[tid].z += o.z; red[tid].w += o.w;
        }
        __syncthreads();
    }
    if (tid < 4) {
        float4 a = red[tid];
        a.x *= inv; a.y *= inv; a.z *= inv; a.w *= inv;
        ((float4*)(out + b * D + slice * SLW))[tid] = a;
    }
}

extern "C" void kernel_launch(void* const* d_in, const int* in_sizes, int n_in,
                              void* d_out, int out_size, void* d_ws, size_t ws_size,
                              hipStream_t stream) {
    const float* Q  = (const float*)d_in[0];
    const float* K  = (const float*)d_in[1];
    const float* V  = (const float*)d_in[2];
    const float* Wk = (const float*)d_in[3];
    const float* bk = (const float*)d_in[4];
    const float* Wq = (const float*)d_in[5];
    const float* bq = (const float*)d_in[6];
    const float* Wh = (const float*)d_in[7];
    const float* bh = (const float*)d_in[8];

    float* out  = (float*)d_out;               // [32, 512]
    float* wout = out + NB * D;                // [32, 2048]

    float* ws    = (float*)d_ws;
    float* wkh   = ws;                         // 512
    float* wqh   = ws + 512;                   // 512
    float* cbias = ws + 1024;                  // 1 (pad to 64)
    float* pbuf  = ws + 1088;                  // 65536 (16B aligned)

    prep_kernel<<<D + 1, 256, 0, stream>>>(Wk, Wq, Wh, bk, bq, bh, wkh, wqh, cbias);
    energy_kernel<<<(NB * NKEYS) / 8, 256, 0, stream>>>(K, Q, wkh, wqh, cbias, pbuf);
    vfinal_kernel<<<NB * NSLICE, 256, 0, stream>>>(V, pbuf, out, wout);
}

// Round 13
// 53.470 us; speedup vs baseline: 1.3329x; 1.3329x over previous
//
#include <hip/hip_runtime.h>

#define NB     32
#define NKEYS  2048
#define D      512
#define NSLICE 16                  // v-slices per batch (32 floats = 128B each)
#define SLW    (D / NSLICE)        // 32 floats = 8 float4 per slice

__device__ __forceinline__ float wave_sum(float v) {
    #pragma unroll
    for (int o = 32; o > 0; o >>= 1) v += __shfl_xor(v, o);
    return v;
}
__device__ __forceinline__ float dot8(float4 a, float4 b, float4 c, float4 d) {
    return a.x * b.x + a.y * b.y + a.z * b.z + a.w * b.w
         + c.x * d.x + c.y * d.y + c.z * d.z + c.w * d.w;
}

// blocks 0..511: wkh[dk] = Wk[dk,:]·Wh ; wqh[dk] = Wq[dk,:]·Wh
// block 512:     cbias = (bk+bq)·Wh + bh
__global__ __launch_bounds__(256) void prep_kernel(const float* __restrict__ Wk,
        const float* __restrict__ Wq, const float* __restrict__ Wh,
        const float* __restrict__ bk, const float* __restrict__ bq,
        const float* __restrict__ bh,
        float* __restrict__ wkh, float* __restrict__ wqh, float* __restrict__ cbias) {
    int tid = threadIdx.x, lane = tid & 63, wv = tid >> 6;
    __shared__ float sred[8];
    if (blockIdx.x < D) {
        int dk = blockIdx.x;
        float sk = 0.f, sq = 0.f;
        #pragma unroll
        for (int h = tid; h < D; h += 256) {
            float wh = Wh[h];
            sk = fmaf(Wk[dk * D + h], wh, sk);
            sq = fmaf(Wq[dk * D + h], wh, sq);
        }
        sk = wave_sum(sk); sq = wave_sum(sq);
        if (lane == 0) { sred[wv] = sk; sred[wv + 4] = sq; }
        __syncthreads();
        if (tid == 0) wkh[dk] = sred[0] + sred[1] + sred[2] + sred[3];
        if (tid == 1) wqh[dk] = sred[4] + sred[5] + sred[6] + sred[7];
    } else {
        float s = 0.f;
        #pragma unroll
        for (int h = tid; h < D; h += 256) s = fmaf(bk[h] + bq[h], Wh[h], s);
        s = wave_sum(s);
        if (lane == 0) sred[wv] = s;
        __syncthreads();
        if (tid == 0) cbias[0] = sred[0] + sred[1] + sred[2] + sred[3] + bh[0];
    }
}

// p[b,n] = exp(relu(K[b,n,:]·wkh + qd_b)); qd computed by wave 0 per block
// (blocks never straddle batches: 512 blocks/batch). K loads issue before the
// barrier, so the stream is undisturbed. grid: 16384 blocks x 256 threads.
__global__ __launch_bounds__(256) void energy_kernel(const float* __restrict__ K,
        const float* __restrict__ Q, const float* __restrict__ wkh,
        const float* __restrict__ wqh, const float* __restrict__ cbias,
        float* __restrict__ p) {
    int tid  = threadIdx.x;
    int lane = tid & 63, wv = tid >> 6;
    long row0 = (long)blockIdx.x * 4;
    int b = (int)(row0 >> 11);
    __shared__ float qds;

    // issue this wave's K loads first (independent of the barrier)
    const float4* kr = (const float4*)(K + (row0 + wv) * D);
    const float4* wr = (const float4*)wkh;
    float4 k0 = kr[lane], k1 = kr[lane + 64];
    float4 w0 = wr[lane], w1 = wr[lane + 64];

    if (wv == 0) {                                   // wave 0: qd for batch b
        const float4* q4  = (const float4*)(Q + b * D);
        const float4* wq4 = (const float4*)wqh;
        float qd = dot8(q4[lane], wq4[lane], q4[lane + 64], wq4[lane + 64]);
        qd = wave_sum(qd);
        if (lane == 0) qds = qd + cbias[0];
    }

    float s = dot8(k0, w0, k1, w1);
    s = wave_sum(s);
    __syncthreads();                                 // qds ready
    // relu bounds energies; exp without max-shift is fp32-safe and cancels
    // identically after normalization.
    if (lane == 0) p[row0 + wv] = expf(fmaxf(s + qds, 0.f));
}

// Block (b, slice): S_b from LDS-cached p (8KB, L2-hot), stream V[b,:,slice]
// (128B-aligned float4 reads), write FINAL out slice + wout strip.
// 512 threads/block -> 16 waves/CU (was 8 in R11).
// grid: NB*NSLICE = 512 blocks x 512 threads.
__global__ __launch_bounds__(512) void vfinal_kernel(const float* __restrict__ V,
        const float* __restrict__ p, float* __restrict__ out,
        float* __restrict__ wout) {
    int slice = blockIdx.x & (NSLICE - 1);
    int b     = blockIdx.x >> 4;
    int tid   = threadIdx.x, lane = tid & 63, wv = tid >> 6;

    __shared__ float pl[NKEYS];                      // 8 KB
    __shared__ float sredf[8];
    __shared__ float4 red[512];                      // 8 KB

    // load p[b,:] to LDS + block sum (one float4 per thread)
    const float4* p4 = (const float4*)(p + b * NKEYS);
    float4* pl4 = (float4*)pl;
    float4 pv = p4[tid];
    pl4[tid] = pv;
    float s = pv.x + pv.y + pv.z + pv.w;
    s = wave_sum(s);
    if (lane == 0) sredf[wv] = s;
    __syncthreads();
    float inv = 1.f / (sredf[0] + sredf[1] + sredf[2] + sredf[3]
                     + sredf[4] + sredf[5] + sredf[6] + sredf[7]);

    // V stream: thread owns float4 slot v4i (128B-contiguous per row-chunk),
    // row-group rg (64 rows per pass)
    int v4i = tid & 7;                               // 0..7
    int rg  = tid >> 3;                              // 0..63
    const float4* vb = (const float4*)(V + (long)b * NKEYS * D);
    int colbase = slice * (SLW / 4);                 // slice*8
    float4 acc = {0.f, 0.f, 0.f, 0.f};
    #pragma unroll 8
    for (int pass = 0; pass < NKEYS / 64; ++pass) {  // 32 passes
        int n = pass * 64 + rg;
        float w = pl[n];
        float4 vv = vb[(long)n * (D / 4) + colbase + v4i];
        acc.x = fmaf(w, vv.x, acc.x);
        acc.y = fmaf(w, vv.y, acc.y);
        acc.z = fmaf(w, vv.z, acc.z);
        acc.w = fmaf(w, vv.w, acc.w);
    }

    // wout strip: 128 weights per block (off the critical path)
    int n0 = slice * (NKEYS / NSLICE);
    if (tid < NKEYS / NSLICE) wout[b * NKEYS + n0 + tid] = pl[n0 + tid] * inv;

    // tree-combine 64 row-groups per v4 slot
    red[tid] = acc;
    __syncthreads();
    #pragma unroll
    for (int g = 256; g >= 8; g >>= 1) {
        if (tid < g) {
            float4 o = red[tid + g];
            red[tid].x += o.x; red[tid].y += o.y;
            red[tid].z += o.z; red[tid].w += o.w;
        }
        __syncthreads();
    }
    if (tid < 8) {
        float4 a = red[tid];
        a.x *= inv; a.y *= inv; a.z *= inv; a.w *= inv;
        ((float4*)(out + b * D + slice * SLW))[tid] = a;
    }
}

extern "C" void kernel_launch(void* const* d_in, const int* in_sizes, int n_in,
                              void* d_out, int out_size, void* d_ws, size_t ws_size,
                              hipStream_t stream) {
    const float* Q  = (const float*)d_in[0];
    const float* K  = (const float*)d_in[1];
    const float* V  = (const float*)d_in[2];
    const float* Wk = (const float*)d_in[3];
    const float* bk = (const float*)d_in[4];
    const float* Wq = (const float*)d_in[5];
    const float* bq = (const float*)d_in[6];
    const float* Wh = (const float*)d_in[7];
    const float* bh = (const float*)d_in[8];

    float* out  = (float*)d_out;               // [32, 512]
    float* wout = out + NB * D;                // [32, 2048]

    float* ws    = (float*)d_ws;
    float* wkh   = ws;                         // 512
    float* wqh   = ws + 512;                   // 512
    float* cbias = ws + 1024;                  // 1 (pad to 64)
    float* pbuf  = ws + 1088;                  // 65536 (16B aligned)

    prep_kernel<<<D + 1, 256, 0, stream>>>(Wk, Wq, Wh, bk, bq, bh, wkh, wqh, cbias);
    energy_kernel<<<(NB * NKEYS) / 4, 256, 0, stream>>>(K, Q, wkh, wqh, cbias, pbuf);
    vfinal_kernel<<<NB * NSLICE, 512, 0, stream>>>(V, pbuf, out, wout);
}

// Round 14
// 52.529 us; speedup vs baseline: 1.3568x; 1.0179x over previous
//
#include <hip/hip_runtime.h>

#define NB     32
#define NKEYS  2048
#define D      512
#define NSLICE 16                  // v-slices per batch (32 floats = 128B each)
#define SLW    (D / NSLICE)        // 32 floats = 8 float4 per slice

__device__ __forceinline__ float wave_sum(float v) {
    #pragma unroll
    for (int o = 32; o > 0; o >>= 1) v += __shfl_xor(v, o);
    return v;
}
__device__ __forceinline__ float dot8(float4 a, float4 b, float4 c, float4 d) {
    return a.x * b.x + a.y * b.y + a.z * b.z + a.w * b.w
         + c.x * d.x + c.y * d.y + c.z * d.z + c.w * d.w;
}

// blocks 0..511: wkh[dk] = Wk[dk,:]·Wh ; wqh[dk] = Wq[dk,:]·Wh
// block 512:     cbias = (bk+bq)·Wh + bh
__global__ __launch_bounds__(256) void prep_kernel(const float* __restrict__ Wk,
        const float* __restrict__ Wq, const float* __restrict__ Wh,
        const float* __restrict__ bk, const float* __restrict__ bq,
        const float* __restrict__ bh,
        float* __restrict__ wkh, float* __restrict__ wqh, float* __restrict__ cbias) {
    int tid = threadIdx.x, lane = tid & 63, wv = tid >> 6;
    __shared__ float sred[8];
    if (blockIdx.x < D) {
        int dk = blockIdx.x;
        float sk = 0.f, sq = 0.f;
        #pragma unroll
        for (int h = tid; h < D; h += 256) {
            float wh = Wh[h];
            sk = fmaf(Wk[dk * D + h], wh, sk);
            sq = fmaf(Wq[dk * D + h], wh, sq);
        }
        sk = wave_sum(sk); sq = wave_sum(sq);
        if (lane == 0) { sred[wv] = sk; sred[wv + 4] = sq; }
        __syncthreads();
        if (tid == 0) wkh[dk] = sred[0] + sred[1] + sred[2] + sred[3];
        if (tid == 1) wqh[dk] = sred[4] + sred[5] + sred[6] + sred[7];
    } else {
        float s = 0.f;
        #pragma unroll
        for (int h = tid; h < D; h += 256) s = fmaf(bk[h] + bq[h], Wh[h], s);
        s = wave_sum(s);
        if (lane == 0) sred[wv] = s;
        __syncthreads();
        if (tid == 0) cbias[0] = sred[0] + sred[1] + sred[2] + sred[3] + bh[0];
    }
}

// p[b,n] = exp(relu(K[b,n,:]·wkh + qd_b)); qd computed by wave 0 per block
// (blocks never straddle batches: 512 blocks/batch). K loads issue before the
// barrier, so the stream is undisturbed. grid: 16384 blocks x 256 threads.
__global__ __launch_bounds__(256) void energy_kernel(const float* __restrict__ K,
        const float* __restrict__ Q, const float* __restrict__ wkh,
        const float* __restrict__ wqh, const float* __restrict__ cbias,
        float* __restrict__ p) {
    int tid  = threadIdx.x;
    int lane = tid & 63, wv = tid >> 6;
    long row0 = (long)blockIdx.x * 4;
    int b = (int)(row0 >> 11);
    __shared__ float qds;

    // issue this wave's K loads first (independent of the barrier)
    const float4* kr = (const float4*)(K + (row0 + wv) * D);
    const float4* wr = (const float4*)wkh;
    float4 k0 = kr[lane], k1 = kr[lane + 64];
    float4 w0 = wr[lane], w1 = wr[lane + 64];

    if (wv == 0) {                                   // wave 0: qd for batch b
        const float4* q4  = (const float4*)(Q + b * D);
        const float4* wq4 = (const float4*)wqh;
        float qd = dot8(q4[lane], wq4[lane], q4[lane + 64], wq4[lane + 64]);
        qd = wave_sum(qd);
        if (lane == 0) qds = qd + cbias[0];
    }

    float s = dot8(k0, w0, k1, w1);
    s = wave_sum(s);
    __syncthreads();                                 // qds ready
    // relu bounds energies; exp without max-shift is fp32-safe and cancels
    // identically after normalization.
    if (lane == 0) p[row0 + wv] = expf(fmaxf(s + qds, 0.f));
}

// Block (b, slice): S_b from LDS-cached p (8KB, L2-hot), stream V[b,:,slice]
// (128B-aligned float4 reads), write FINAL out slice + wout strip.
// grid: NB*NSLICE = 512 blocks x 256 threads.
__global__ __launch_bounds__(256) void vfinal_kernel(const float* __restrict__ V,
        const float* __restrict__ p, float* __restrict__ out,
        float* __restrict__ wout) {
    int slice = blockIdx.x & (NSLICE - 1);
    int b     = blockIdx.x >> 4;
    int tid   = threadIdx.x, lane = tid & 63, wv = tid >> 6;

    __shared__ float pl[NKEYS];                      // 8 KB
    __shared__ float sredf[4];
    __shared__ float4 red[256];                      // 4 KB

    // load p[b,:] to LDS + block sum
    const float4* p4 = (const float4*)(p + b * NKEYS);
    float4* pl4 = (float4*)pl;
    float s = 0.f;
    #pragma unroll
    for (int i = 0; i < 2; ++i) {
        float4 v = p4[tid + i * 256];
        pl4[tid + i * 256] = v;
        s += v.x + v.y + v.z + v.w;
    }
    s = wave_sum(s);
    if (lane == 0) sredf[wv] = s;
    __syncthreads();
    float inv = 1.f / (sredf[0] + sredf[1] + sredf[2] + sredf[3]);

    // wout strip: 128 weights per block
    int n0 = slice * (NKEYS / NSLICE);
    if (tid < NKEYS / NSLICE) wout[b * NKEYS + n0 + tid] = pl[n0 + tid] * inv;

    // V stream: thread owns float4 v4i of the slice, row-group rg (32 rows/pass)
    int v4i = tid & 7;                               // 0..7
    int rg  = tid >> 3;                              // 0..31
    const float4* vb = (const float4*)(V + (long)b * NKEYS * D);
    int colbase = slice * (SLW / 4);                 // slice*8
    float4 acc = {0.f, 0.f, 0.f, 0.f};
    #pragma unroll 8
    for (int pass = 0; pass < NKEYS / 32; ++pass) {
        int n = pass * 32 + rg;
        float w = pl[n];
        float4 vv = vb[(long)n * (D / 4) + colbase + v4i];
        acc.x = fmaf(w, vv.x, acc.x);
        acc.y = fmaf(w, vv.y, acc.y);
        acc.z = fmaf(w, vv.z, acc.z);
        acc.w = fmaf(w, vv.w, acc.w);
    }

    // combine 32 row-groups per v4 slot
    red[tid] = acc;
    __syncthreads();
    if (tid < 8) {
        float4 a = red[tid];
        #pragma unroll
        for (int g = 1; g < 32; ++g) {
            float4 c = red[g * 8 + tid];
            a.x += c.x; a.y += c.y; a.z += c.z; a.w += c.w;
        }
        a.x *= inv; a.y *= inv; a.z *= inv; a.w *= inv;
        ((float4*)(out + b * D + slice * SLW))[tid] = a;
    }
}

extern "C" void kernel_launch(void* const* d_in, const int* in_sizes, int n_in,
                              void* d_out, int out_size, void* d_ws, size_t ws_size,
                              hipStream_t stream) {
    const float* Q  = (const float*)d_in[0];
    const float* K  = (const float*)d_in[1];
    const float* V  = (const float*)d_in[2];
    const float* Wk = (const float*)d_in[3];
    const float* bk = (const float*)d_in[4];
    const float* Wq = (const float*)d_in[5];
    const float* bq = (const float*)d_in[6];
    const float* Wh = (const float*)d_in[7];
    const float* bh = (const float*)d_in[8];

    float* out  = (float*)d_out;               // [32, 512]
    float* wout = out + NB * D;                // [32, 2048]

    float* ws    = (float*)d_ws;
    float* wkh   = ws;                         // 512
    float* wqh   = ws + 512;                   // 512
    float* cbias = ws + 1024;                  // 1 (pad to 64)
    float* pbuf  = ws + 1088;                  // 65536 (16B aligned)

    prep_kernel<<<D + 1, 256, 0, stream>>>(Wk, Wq, Wh, bk, bq, bh, wkh, wqh, cbias);
    energy_kernel<<<(NB * NKEYS) / 4, 256, 0, stream>>>(K, Q, wkh, wqh, cbias, pbuf);
    vfinal_kernel<<<NB * NSLICE, 256, 0, stream>>>(V, pbuf, out, wout);
}